// Round 2
// baseline (6865.488 us; speedup 1.0000x reference)
//
#include <hip/hip_runtime.h>
#include <cstdint>

// VAN checkerboard sampler, LEVEL=0, B=4096, L=16, H=32, K=5.
// Maintained-a2 incremental design: conv3 reads persistent a2 field; the 640K-MAC
// conv2 delta-update runs only when the sampled pixel actually changes (~50%).
// a2 accumulation is Kahan-compensated (s_cmp) to keep sampling bit-exact vs ref.
// All reductions deterministic (graph replay must revalidate identically).

struct U2 { uint32_t x, y; };

// JAX Threefry-2x32 (20 rounds) — verified bit-exact in round 1
__device__ __forceinline__ U2 tf2x32(uint32_t k0, uint32_t k1, uint32_t x0, uint32_t x1) {
  uint32_t k2 = k0 ^ k1 ^ 0x1BD11BDAu;
#define TFROT(r) { x0 += x1; x1 = (x1 << (r)) | (x1 >> (32 - (r))); x1 ^= x0; }
  x0 += k0; x1 += k1;
  TFROT(13) TFROT(15) TFROT(26) TFROT(6)
  x0 += k1; x1 += k2 + 1u;
  TFROT(17) TFROT(29) TFROT(16) TFROT(24)
  x0 += k2; x1 += k0 + 2u;
  TFROT(13) TFROT(15) TFROT(26) TFROT(6)
  x0 += k0; x1 += k1 + 3u;
  TFROT(17) TFROT(29) TFROT(16) TFROT(24)
  x0 += k1; x1 += k2 + 4u;
  TFROT(13) TFROT(15) TFROT(26) TFROT(6)
  x0 += k2; x1 += k0 + 5u;
#undef TFROT
  return {x0, x1};
}

__device__ __forceinline__ float lrelu(float v) { return fmaxf(v, 0.1f * v); }

__launch_bounds__(1024, 4)
__global__ void van_kernel(const float* __restrict__ gx,
                           const float* __restrict__ gw1, const float* __restrict__ gb1,
                           const float* __restrict__ gw2, const float* __restrict__ gb2,
                           const float* __restrict__ gw3, const float* __restrict__ gb3,
                           float* __restrict__ out, int B) {
  __shared__ __align__(16) float s_xf[784];        // x with +/-6 circular halo (28x28)
  __shared__ __align__(16) float s_w1[800];
  __shared__ __align__(16) float s_w3[800];
  __shared__ float s_b1[32], s_b2[32];
  __shared__ float s_u[64];
  __shared__ float s_c3[16];
  __shared__ __align__(16) float s_h1d[800];       // delta_h1: [pos25][ic32]
  __shared__ __align__(16) float s_a2[8192];       // a2 (+b2): [(row*16+col)*32+oc]
  __shared__ __align__(16) float s_pool[8192];     // init: h1f [(pos)*32+ic]; main: Kahan comp
  __shared__ __align__(16) float s_buf[16][864];   // per-wave staging buffers

  const int tid  = threadIdx.x;
  const int bg   = blockIdx.x;
  const int lane = tid & 63;
  const int wv   = tid >> 6;
  const int oc   = tid & 31;   // conv2 out-channel (phase B / w2r ownership)
  const int ic   = tid >> 5;   // conv2 in-channel  (phase B)

  // ---------------- setup ----------------
  const float b3v = gb3[0];
  float w2r[25];
  {
    const float* p = gw2 + (oc * 32 + ic) * 25;    // w2[oc][ic][ky][kx]
    #pragma unroll
    for (int k = 0; k < 25; ++k) w2r[k] = p[k];
  }
  if (tid < 800) { s_w1[tid] = gw1[tid]; s_w3[tid] = gw3[tid]; }
  if (tid < 32)  { s_b1[tid] = gb1[tid]; s_b2[tid] = gb2[tid]; }
  if (tid < 784) {
    int rr = tid / 28, cc = tid - rr * 28;
    s_xf[tid] = gx[bg * 256 + ((rr - 6) & 15) * 16 + ((cc - 6) & 15)];
  }
  if (tid < 64) {
    U2 key = tf2x32(0u, 42u, 0u, (uint32_t)tid);
    U2 tt  = tf2x32(key.x, key.y, 0u, (uint32_t)bg);
    uint32_t bits = tt.x ^ tt.y;
    s_u[tid] = __uint_as_float(0x3F800000u | (bits >> 9)) - 1.0f;
  }
  __syncthreads();

  // ---------------- init: full h1 field into s_pool ----------------
  {
    const int icI = tid & 31, pg = tid >> 5;       // 32 ic x 32 pos-groups
    float w1r[25];
    #pragma unroll
    for (int k = 0; k < 25; ++k) w1r[k] = s_w1[icI * 25 + k];
    const float b1v = s_b1[icI];
    #pragma unroll
    for (int rep = 0; rep < 8; ++rep) {
      int pos = pg * 8 + rep;
      int r = pos >> 4, c = pos & 15;
      float a = b1v;
      #pragma unroll
      for (int ky = 0; ky < 5; ++ky)
        #pragma unroll
        for (int kx = 0; kx < 5; ++kx)
          a = fmaf(s_xf[(r + ky + 4) * 28 + (c + kx + 4)], w1r[ky * 5 + kx], a);
      s_pool[pos * 32 + icI] = lrelu(a);
    }
  }
  __syncthreads();

  // ---------------- init: full a2 field (+b2), 16 chunks of 1 row ----------------
  #pragma unroll 1
  for (int cr = 0; cr < 16; ++cr) {
    float acc[16];
    #pragma unroll
    for (int t = 0; t < 16; ++t) acc[t] = 0.f;
    #pragma unroll
    for (int ky = 0; ky < 5; ++ky) {
      int row = (cr + ky - 2) & 15;
      float h[16];
      #pragma unroll
      for (int col = 0; col < 16; ++col) h[col] = s_pool[(row * 16 + col) * 32 + ic];
      #pragma unroll
      for (int kx = 0; kx < 5; ++kx) {
        float w = w2r[ky * 5 + kx];
        #pragma unroll
        for (int X = 0; X < 16; ++X)
          acc[X] = fmaf(h[(X + kx - 2) & 15], w, acc[X]);
      }
    }
    #pragma unroll
    for (int t = 0; t < 16; ++t) acc[t] += __shfl_xor(acc[t], 32, 64);
    if (lane < 32) {
      #pragma unroll
      for (int t = 0; t < 16; ++t) s_buf[wv][t * 32 + lane] = acc[t];
    }
    __syncthreads();
    if (tid < 512) {
      float sm = 0.f;
      #pragma unroll
      for (int v = 0; v < 16; ++v) sm += s_buf[v][tid];
      s_a2[cr * 512 + tid] = sm + s_b2[tid & 31];
    }
    __syncthreads();
  }
  // zero Kahan compensation (s_pool reused; h1f no longer needed)
  #pragma unroll
  for (int k = 0; k < 8; ++k) s_pool[k * 1024 + tid] = 0.f;
  __syncthreads();

  // ---------------- main autoregressive loop ----------------
  float logq = 0.f;
  #pragma unroll 1
  for (int s = 0; s < 64; ++s) {
    const int i = 2 * (s >> 3) + 1;
    const int j = 2 * (s & 7) + 1;

    // ---- conv3 from maintained a2 ----
    float v3 = 0.f;
    if (tid < 800) {
      int p = tid >> 5, o2 = tid & 31;
      int dy = p / 5, dx = p - 5 * dy;
      int idx = (((i + dy - 2) & 15) * 16 + ((j + dx - 2) & 15)) * 32 + o2;
      float a2v = s_a2[idx] - s_pool[idx];   // Kahan-corrected value
      v3 = lrelu(a2v) * s_w3[o2 * 25 + p];
    }
    #pragma unroll
    for (int m = 32; m >= 1; m >>= 1) v3 += __shfl_xor(v3, m, 64);
    if (lane == 0) s_c3[wv] = v3;
    __syncthreads();                                    // (A)

    // ---- sample (all threads, redundant & identical) ----
    float logit = b3v;
    #pragma unroll
    for (int v = 0; v < 16; ++v) logit += s_c3[v];
    const float pr   = 1.f / (1.f + expf(-logit));
    const float u    = s_u[s];
    const float samp = (u < pr) ? 1.f : -1.f;
    const float xold = s_xf[(i + 6) * 28 + (j + 6)];
    logq += (samp > 0.f) ? logf(pr + 1e-7f) : logf(1.f - pr + 1e-7f);

    if (samp == xold) { __syncthreads(); continue; }    // block-uniform skip (~50%)

    // ---- phase A: delta_h1 at 25 positions x 32 ic ----
    if (tid < 800) {
      int p = tid >> 5, icA = tid & 31;
      int dyq = p / 5, dxq = p - 5 * dyq;
      const float* wp = &s_w1[icA * 25];
      float a1v = s_b1[icA];
      int base = (i + dyq + 2) * 28 + (j + dxq + 2);
      #pragma unroll
      for (int ky = 0; ky < 5; ++ky)
        #pragma unroll
        for (int kx = 0; kx < 5; ++kx)
          a1v = fmaf(s_xf[base + ky * 28 + kx], wp[ky * 5 + kx], a1v);
      float delta = samp - xold;                        // +/-2
      float a1n = fmaf(delta, wp[(4 - dyq) * 5 + (4 - dxq)], a1v);
      s_h1d[p * 32 + icA] = lrelu(a1n) - lrelu(a1v);
    }
    __syncthreads();                                    // (C)

    if (tid == 1023) {                                  // update x halo copies
      int r1 = i + 6, c1 = j + 6;
      int r2 = (i < 6) ? i + 22 : ((i >= 10) ? i - 10 : r1);
      int c2 = (j < 6) ? j + 22 : ((j >= 10) ? j - 10 : c1);
      s_xf[r1 * 28 + c1] = samp; s_xf[r1 * 28 + c2] = samp;
      s_xf[r2 * 28 + c1] = samp; s_xf[r2 * 28 + c2] = samp;
    }

    float h1d[25];
    #pragma unroll
    for (int q = 0; q < 25; ++q) h1d[q] = s_h1d[q * 32 + ic];

    // ---- phase B: 5x5 delta_h1 (*) w2 -> 9x9 a2 update, 3 chunks of 3 rows ----
    #pragma unroll
    for (int cch = 0; cch < 3; ++cch) {
      float acc[27];
      #pragma unroll
      for (int t = 0; t < 27; ++t) acc[t] = 0.f;
      #pragma unroll
      for (int u2 = 0; u2 < 3; ++u2) {
        const int U = 3 * cch + u2;                     // output row offset 0..8
        #pragma unroll
        for (int dyp = 0; dyp < 5; ++dyp) {
          const int ky = dyp + 4 - U;
          if (ky < 0 || ky > 4) continue;               // folds at compile time
          #pragma unroll
          for (int kx = 0; kx < 5; ++kx) {
            const float w = w2r[ky * 5 + kx];
            #pragma unroll
            for (int dxp = 0; dxp < 5; ++dxp)
              acc[u2 * 9 + (dxp - kx + 4)] = fmaf(h1d[dyp * 5 + dxp], w, acc[u2 * 9 + (dxp - kx + 4)]);
          }
        }
      }
      #pragma unroll
      for (int t = 0; t < 27; ++t) acc[t] += __shfl_xor(acc[t], 32, 64);
      if (lane < 32) {
        #pragma unroll
        for (int t = 0; t < 27; ++t) s_buf[wv][t * 32 + lane] = acc[t];
      }
      __syncthreads();
      if (tid < 864) {
        float sm = 0.f;
        #pragma unroll
        for (int v = 0; v < 16; ++v) sm += s_buf[v][tid];
        int u3 = tid / 288, rem = tid - u3 * 288;
        int V = rem >> 5, o3 = rem & 31;
        int idx = (((i - 4 + 3 * cch + u3) & 15) * 16 + ((j - 4 + V) & 15)) * 32 + o3;
        // Kahan compensated accumulate: a2 += sm
        float y  = sm - s_pool[idx];
        float a  = s_a2[idx];
        float t2 = a + y;
        s_pool[idx] = (t2 - a) - y;
        s_a2[idx] = t2;
      }
      __syncthreads();
    }
  }

  // ---------------- output ----------------
  if (tid < 256)
    out[bg * 256 + tid] = s_xf[((tid >> 4) + 6) * 28 + (tid & 15) + 6];
  if (tid == 0)
    out[B * 256 + bg] = logq;
}

extern "C" void kernel_launch(void* const* d_in, const int* in_sizes, int n_in,
                              void* d_out, int out_size, void* d_ws, size_t ws_size,
                              hipStream_t stream) {
  const float* gx  = (const float*)d_in[0];
  const float* gw1 = (const float*)d_in[1];
  const float* gb1 = (const float*)d_in[2];
  const float* gw2 = (const float*)d_in[3];
  const float* gb2 = (const float*)d_in[4];
  const float* gw3 = (const float*)d_in[5];
  const float* gb3 = (const float*)d_in[6];
  float* out = (float*)d_out;
  const int B = in_sizes[0] / 256;

  hipLaunchKernelGGL(van_kernel, dim3(B), dim3(1024), 0, stream,
                     gx, gw1, gb1, gw2, gb2, gw3, gb3, out, B);
}